// Round 2
// baseline (707.686 us; speedup 1.0000x reference)
//
#include <hip/hip_runtime.h>
#include <stdint.h>

// NSGCN: 3-layer GraphConv (norm='both'), N=50000 nodes, E=800000 edges.
// Reordering: (segsum((h*ns)[src]) * nd) @ W + b  ==  segsum(((h*ns)@W)[src]) * nd + b
// (row-scale and segment_sum commute with right-matmul). So per layer:
//   t = (h * norm_src) @ W          (dense GEMM, LDS-staged, fp32 VALU)
//   h' = act(segsum_dst(t[src]) * norm_dst + b)   (CSR gather, no float atomics)
// CSR built per call in d_ws: histogram -> 3-phase scan -> counting-sort scatter.
// Note: scatter placement order within a row is atomic-order nondeterministic ->
// summation order varies by ~1e-6 relative fp32 noise, far below the 4.7e-3 threshold.

// ---------------- degree histogram ----------------
__global__ void hist_kernel(const int* __restrict__ src, const int* __restrict__ dst,
                            int* __restrict__ deg_out, int* __restrict__ deg_in, int E) {
    int e = blockIdx.x * blockDim.x + threadIdx.x;
    if (e >= E) return;
    atomicAdd(&deg_out[src[e]], 1);
    atomicAdd(&deg_in[dst[e]], 1);
}

// ---------------- scan phase 1: per-1024-block exclusive scan ----------------
__global__ void scan1_kernel(const int* __restrict__ deg, int* __restrict__ excl,
                             int* __restrict__ blocksum, int n) {
    int i = blockIdx.x * 1024 + threadIdx.x;
    int v = (i < n) ? deg[i] : 0;
    int lane = threadIdx.x & 63;
    int wid  = threadIdx.x >> 6;
    int incl = v;
    #pragma unroll
    for (int off = 1; off < 64; off <<= 1) {
        int t = __shfl_up(incl, off, 64);
        if (lane >= off) incl += t;
    }
    __shared__ int wsum[16];
    if (lane == 63) wsum[wid] = incl;
    __syncthreads();
    if (threadIdx.x < 16) {
        int wv = wsum[threadIdx.x];
        #pragma unroll
        for (int off = 1; off < 16; off <<= 1) {
            int t = __shfl_up(wv, off, 64);
            if ((int)threadIdx.x >= off) wv += t;
        }
        wsum[threadIdx.x] = wv;   // inclusive wave-sums
    }
    __syncthreads();
    int waveoff = (wid > 0) ? wsum[wid - 1] : 0;
    if (i < n) excl[i] = waveoff + incl - v;
    if (threadIdx.x == 1023) blocksum[blockIdx.x] = wsum[15];
}

// ---------------- scan phase 2: scan the (<=64) block sums ----------------
__global__ void scan2_kernel(const int* __restrict__ blocksum, int* __restrict__ blockoff,
                             int nb, int* __restrict__ total_out) {
    int i = threadIdx.x;
    int v = (i < nb) ? blocksum[i] : 0;
    int incl = v;
    #pragma unroll
    for (int off = 1; off < 64; off <<= 1) {
        int t = __shfl_up(incl, off, 64);
        if (i >= off) incl += t;
    }
    if (i < nb) blockoff[i] = incl - v;
    if (i == 63) *total_out = incl;    // row_off[N] = E
}

// ---------------- scan phase 3 + norms ----------------
__global__ void scan3_norm_kernel(int* __restrict__ row_off, const int* __restrict__ blockoff,
                                  int* __restrict__ row_pos,
                                  const int* __restrict__ deg_out, const int* __restrict__ deg_in,
                                  float* __restrict__ ns, float* __restrict__ nd, int n) {
    int i = blockIdx.x * blockDim.x + threadIdx.x;
    if (i >= n) return;
    int v = row_off[i] + blockoff[i >> 10];
    row_off[i] = v;
    row_pos[i] = v;
    int a = deg_out[i]; if (a < 1) a = 1;
    int b = deg_in[i];  if (b < 1) b = 1;
    ns[i] = 1.0f / sqrtf((float)a);
    nd[i] = 1.0f / sqrtf((float)b);
}

// ---------------- counting-sort scatter: edge ids bucketed by dst ----------------
__global__ void scatter_kernel(const int* __restrict__ src, const int* __restrict__ dst,
                               int* __restrict__ row_pos, int* __restrict__ src_sorted, int E) {
    int e = blockIdx.x * blockDim.x + threadIdx.x;
    if (e >= E) return;
    int d = dst[e];
    int p = atomicAdd(&row_pos[d], 1);
    src_sorted[p] = src[e];
}

// ---------------- fused rowscale + dense GEMM: T = (H * ns) @ W ----------------
// block = 256 threads = 4 waves; 16 nodes per block (4 nodes per wave, lane = out feature)
template <int FIN, int FOUT>
__global__ void rowscale_gemm(const float* __restrict__ H, const float* __restrict__ ns,
                              const float* __restrict__ Wg, float* __restrict__ T, int n) {
    __shared__ float Wlds[FIN * FOUT];
    __shared__ float rows[16][FIN];
    for (int i = threadIdx.x; i < FIN * FOUT; i += 256) Wlds[i] = Wg[i];
    int node0 = blockIdx.x * 16;
    for (int idx = threadIdx.x; idx < 16 * FIN; idx += 256) {
        int rr = idx / FIN, k = idx - rr * FIN;
        int node = node0 + rr;
        rows[rr][k] = (node < n) ? H[(size_t)node * FIN + k] * ns[node] : 0.0f;
    }
    __syncthreads();
    int w = threadIdx.x >> 6;       // wave 0..3
    int lane = threadIdx.x & 63;    // output feature
    if (lane < FOUT) {
        float acc[4] = {0.f, 0.f, 0.f, 0.f};
        for (int k = 0; k < FIN; ++k) {
            float wv = Wlds[k * FOUT + lane];
            #pragma unroll
            for (int i = 0; i < 4; ++i) acc[i] += rows[w * 4 + i][k] * wv;
        }
        #pragma unroll
        for (int i = 0; i < 4; ++i) {
            int node = node0 + w * 4 + i;
            if (node < n) T[(size_t)node * FOUT + lane] = acc[i];
        }
    }
}

// ---------------- CSR aggregation: one wave per dst node ----------------
template <int F, bool RELU>
__global__ void agg_kernel(const float* __restrict__ T, const int* __restrict__ row_off,
                           const int* __restrict__ src_sorted, const float* __restrict__ nd,
                           const float* __restrict__ bias, float* __restrict__ Hout, int n) {
    int gid = blockIdx.x * blockDim.x + threadIdx.x;
    int node = gid >> 6;
    int lane = gid & 63;
    if (node >= n) return;
    int beg = row_off[node], end = row_off[node + 1];
    float acc0 = 0.f, acc1 = 0.f;
    int e = beg;
    for (; e + 2 <= end; e += 2) {
        int s0 = src_sorted[e];
        int s1 = src_sorted[e + 1];
        if (lane < F) {
            acc0 += T[(size_t)s0 * F + lane];
            acc1 += T[(size_t)s1 * F + lane];
        }
    }
    if (e < end) {
        int s0 = src_sorted[e];
        if (lane < F) acc0 += T[(size_t)s0 * F + lane];
    }
    if (lane < F) {
        float v = (acc0 + acc1) * nd[node] + bias[lane];
        if (RELU) v = fmaxf(v, 0.f);
        Hout[(size_t)node * F + lane] = v;
    }
}

extern "C" void kernel_launch(void* const* d_in, const int* in_sizes, int n_in,
                              void* d_out, int out_size, void* d_ws, size_t ws_size,
                              hipStream_t stream) {
    const float* x  = (const float*)d_in[0];
    const float* W0 = (const float*)d_in[1];
    const float* b0 = (const float*)d_in[2];
    const float* W1 = (const float*)d_in[3];
    const float* b1 = (const float*)d_in[4];
    const float* W2 = (const float*)d_in[5];
    const float* b2 = (const float*)d_in[6];
    const int* src  = (const int*)d_in[7];
    const int* dst  = (const int*)d_in[8];
    float* out = (float*)d_out;

    const int N = 50000;
    const int E = in_sizes[7];
    const int NB = (N + 1023) / 1024;   // 49 scan blocks (<=64 for single-wave phase 2)

    // ---- workspace layout (ints first, then 16B-aligned floats) ----
    int* p = (int*)d_ws;
    int* deg_out    = p;  p += N;
    int* deg_in     = p;  p += N;
    int* row_off    = p;  p += N + 1;
    int* row_pos    = p;  p += N;
    int* blocksum   = p;  p += NB;
    int* blockoff   = p;  p += NB;
    int* src_sorted = p;  p += E;
    uintptr_t fp = ((uintptr_t)p + 15) & ~(uintptr_t)15;
    float* f = (float*)fp;
    float* norm_src = f;  f += N;
    float* norm_dst = f;  f += N;
    float* t_buf    = f;  f += (size_t)N * 64;
    float* h_buf    = f;  f += (size_t)N * 64;

    // deg arrays are the first 2*N ints of ws
    hipMemsetAsync(deg_out, 0, (size_t)2 * N * sizeof(int), stream);

    hist_kernel<<<(E + 255) / 256, 256, 0, stream>>>(src, dst, deg_out, deg_in, E);
    scan1_kernel<<<NB, 1024, 0, stream>>>(deg_in, row_off, blocksum, N);
    scan2_kernel<<<1, 64, 0, stream>>>(blocksum, blockoff, NB, &row_off[N]);
    scan3_norm_kernel<<<(N + 255) / 256, 256, 0, stream>>>(
        row_off, blockoff, row_pos, deg_out, deg_in, norm_src, norm_dst, N);
    scatter_kernel<<<(E + 255) / 256, 256, 0, stream>>>(src, dst, row_pos, src_sorted, E);

    const int gemm_grid = (N + 15) / 16;
    const int agg_grid  = (N * 64 + 255) / 256;

    // layer 0: x[50000,100] -> h[50000,64], relu
    rowscale_gemm<100, 64><<<gemm_grid, 256, 0, stream>>>(x, norm_src, W0, t_buf, N);
    agg_kernel<64, true><<<agg_grid, 256, 0, stream>>>(t_buf, row_off, src_sorted,
                                                       norm_dst, b0, h_buf, N);
    // layer 1: 64 -> 64, relu
    rowscale_gemm<64, 64><<<gemm_grid, 256, 0, stream>>>(h_buf, norm_src, W1, t_buf, N);
    agg_kernel<64, true><<<agg_grid, 256, 0, stream>>>(t_buf, row_off, src_sorted,
                                                       norm_dst, b1, h_buf, N);
    // layer 2: 64 -> 47, no activation, write d_out
    rowscale_gemm<64, 47><<<gemm_grid, 256, 0, stream>>>(h_buf, norm_src, W2, t_buf, N);
    agg_kernel<47, false><<<agg_grid, 256, 0, stream>>>(t_buf, row_off, src_sorted,
                                                        norm_dst, b2, out, N);
}

// Round 3
// 312.622 us; speedup vs baseline: 2.2637x; 2.2637x over previous
//
#include <hip/hip_runtime.h>
#include <stdint.h>

// NSGCN: 3-layer GraphConv (norm='both'), N=50000, E=800000.
// Identity: (segsum((h*ns)[src]) * nd) @ W + b == segsum(((h*ns)@W)[src]) * nd + b
// Per layer: t = (h*ns)@W  (dense, LDS-staged, all global access float4)
//            h' = act(segsum_dst(t[src]) * nd + b)   (CSR gather, float4)
// CSR built per call in d_ws (histogram -> scan -> counting-sort scatter).

// ---------------- degree histogram ----------------
__global__ void hist_kernel(const int* __restrict__ src, const int* __restrict__ dst,
                            int* __restrict__ deg_out, int* __restrict__ deg_in, int E) {
    int e = blockIdx.x * blockDim.x + threadIdx.x;
    if (e >= E) return;
    atomicAdd(&deg_out[src[e]], 1);
    atomicAdd(&deg_in[dst[e]], 1);
}

// ---------------- scan phase 1: per-1024-block exclusive scan ----------------
__global__ void scan1_kernel(const int* __restrict__ deg, int* __restrict__ excl,
                             int* __restrict__ blocksum, int n) {
    int i = blockIdx.x * 1024 + threadIdx.x;
    int v = (i < n) ? deg[i] : 0;
    int lane = threadIdx.x & 63;
    int wid  = threadIdx.x >> 6;
    int incl = v;
    #pragma unroll
    for (int off = 1; off < 64; off <<= 1) {
        int t = __shfl_up(incl, off, 64);
        if (lane >= off) incl += t;
    }
    __shared__ int wsum[16];
    if (lane == 63) wsum[wid] = incl;
    __syncthreads();
    if (threadIdx.x < 16) {
        int wv = wsum[threadIdx.x];
        #pragma unroll
        for (int off = 1; off < 16; off <<= 1) {
            int t = __shfl_up(wv, off, 64);
            if ((int)threadIdx.x >= off) wv += t;
        }
        wsum[threadIdx.x] = wv;
    }
    __syncthreads();
    int waveoff = (wid > 0) ? wsum[wid - 1] : 0;
    if (i < n) excl[i] = waveoff + incl - v;
    if (threadIdx.x == 1023) blocksum[blockIdx.x] = wsum[15];
}

// ---------------- scan phase 2 ----------------
__global__ void scan2_kernel(const int* __restrict__ blocksum, int* __restrict__ blockoff,
                             int nb, int* __restrict__ total_out) {
    int i = threadIdx.x;
    int v = (i < nb) ? blocksum[i] : 0;
    int incl = v;
    #pragma unroll
    for (int off = 1; off < 64; off <<= 1) {
        int t = __shfl_up(incl, off, 64);
        if (i >= off) incl += t;
    }
    if (i < nb) blockoff[i] = incl - v;
    if (i == 63) *total_out = incl;
}

// ---------------- scan phase 3 + norms ----------------
__global__ void scan3_norm_kernel(int* __restrict__ row_off, const int* __restrict__ blockoff,
                                  int* __restrict__ row_pos,
                                  const int* __restrict__ deg_out, const int* __restrict__ deg_in,
                                  float* __restrict__ ns, float* __restrict__ nd, int n) {
    int i = blockIdx.x * blockDim.x + threadIdx.x;
    if (i >= n) return;
    int v = row_off[i] + blockoff[i >> 10];
    row_off[i] = v;
    row_pos[i] = v;
    int a = deg_out[i]; if (a < 1) a = 1;
    int b = deg_in[i];  if (b < 1) b = 1;
    ns[i] = 1.0f / sqrtf((float)a);
    nd[i] = 1.0f / sqrtf((float)b);
}

// ---------------- counting-sort scatter ----------------
__global__ void scatter_kernel(const int* __restrict__ src, const int* __restrict__ dst,
                               int* __restrict__ row_pos, int* __restrict__ src_sorted, int E) {
    int e = blockIdx.x * blockDim.x + threadIdx.x;
    if (e >= E) return;
    int d = dst[e];
    int p = atomicAdd(&row_pos[d], 1);
    src_sorted[p] = src[e];
}

// ---------------- fused rowscale + GEMM v2: T = (H * ns) @ W, stride WS ----------------
// 64 nodes/block, 4 waves; wave = 4 node-groups x 16 lanes; lane owns feature quad 4f.
// All global access is float4. W in LDS padded to WS (mult of 4), rows padded stride FIN+4.
template <int FIN, int FOUT>
__global__ __launch_bounds__(256) void rowscale_gemm2(const float* __restrict__ H,
        const float* __restrict__ ns, const float* __restrict__ Wg,
        float* __restrict__ T, int n) {
    constexpr int WS = (FOUT + 3) & ~3;   // 64 or 48
    constexpr int RP = FIN + 4;           // padded row stride (floats), breaks bank alias
    constexpr int Q  = FIN / 4;           // row float4 count (FIN % 4 == 0)
    __shared__ __align__(16) float Wlds[FIN * WS];
    __shared__ __align__(16) float rows[64 * RP];

    // stage W (coalesced scalar; zero-pad cols FOUT..WS)
    for (int i = threadIdx.x; i < FIN * WS; i += 256) {
        int k = i / WS, j = i - k * WS;
        Wlds[i] = (j < FOUT) ? Wg[k * FOUT + j] : 0.0f;
    }
    // stage 64 rows of H, scaled by ns, via float4
    int node0 = blockIdx.x * 64;
    for (int idx = threadIdx.x; idx < 64 * Q; idx += 256) {
        int nl = idx / Q, q = idx - nl * Q;
        int node = node0 + nl;
        float4 v = make_float4(0.f, 0.f, 0.f, 0.f);
        float s = 0.f;
        if (node < n) {
            v = *(const float4*)&H[(size_t)node * FIN + 4 * q];
            s = ns[node];
        }
        float4* d4 = (float4*)&rows[nl * RP + 4 * q];
        d4->x = v.x * s; d4->y = v.y * s; d4->z = v.z * s; d4->w = v.w * s;
    }
    __syncthreads();

    int w = threadIdx.x >> 6;
    int lane = threadIdx.x & 63;
    int g = lane >> 4, f = lane & 15;
    if (4 * f < WS) {
        #pragma unroll
        for (int r = 0; r < 4; ++r) {
            int nl = w * 16 + r * 4 + g;
            const float* rp = &rows[nl * RP];
            float4 acc = make_float4(0.f, 0.f, 0.f, 0.f);
            for (int k = 0; k < FIN; ++k) {
                float hv = rp[k];                               // ds broadcast per group
                float4 wv = *(const float4*)&Wlds[k * WS + 4 * f]; // ds_read_b128
                acc.x += hv * wv.x; acc.y += hv * wv.y;
                acc.z += hv * wv.z; acc.w += hv * wv.w;
            }
            int node = node0 + nl;
            if (node < n)
                *(float4*)&T[(size_t)node * WS + 4 * f] = acc;  // global_store_dwordx4
        }
    }
}

// ---------------- CSR aggregation v2: wave per dst node, float4 gather ----------------
// 4 edge-groups x 16 lanes; lane owns feature quad 4f; cross-group shfl_xor reduce.
template <int TS, int FOUT, bool RELU>
__global__ __launch_bounds__(256) void agg2(const float* __restrict__ T,
        const int* __restrict__ row_off, const int* __restrict__ srcs,
        const float* __restrict__ nd, const float* __restrict__ bias,
        float* __restrict__ Hout, int n) {
    int node = (blockIdx.x * 256 + threadIdx.x) >> 6;
    int lane = threadIdx.x & 63;
    int g = lane >> 4, f = lane & 15;
    if (node >= n) return;
    int beg = row_off[node], end = row_off[node + 1];
    float4 acc = make_float4(0.f, 0.f, 0.f, 0.f);
    if (4 * f < TS) {
        for (int e = beg + g; e < end; e += 4) {
            int s = srcs[e];                                    // broadcast per group
            float4 v = *(const float4*)&T[(size_t)s * TS + 4 * f];
            acc.x += v.x; acc.y += v.y; acc.z += v.z; acc.w += v.w;
        }
    }
    // reduce the 4 groups (lane xor 16, 32) — all lanes participate
    #pragma unroll
    for (int m = 16; m <= 32; m <<= 1) {
        acc.x += __shfl_xor(acc.x, m, 64);
        acc.y += __shfl_xor(acc.y, m, 64);
        acc.z += __shfl_xor(acc.z, m, 64);
        acc.w += __shfl_xor(acc.w, m, 64);
    }
    if (g == 0 && 4 * f < TS) {
        float s = nd[node];
        if (TS == FOUT) {
            float4 o;
            o.x = acc.x * s + bias[4 * f + 0];
            o.y = acc.y * s + bias[4 * f + 1];
            o.z = acc.z * s + bias[4 * f + 2];
            o.w = acc.w * s + bias[4 * f + 3];
            if (RELU) {
                o.x = fmaxf(o.x, 0.f); o.y = fmaxf(o.y, 0.f);
                o.z = fmaxf(o.z, 0.f); o.w = fmaxf(o.w, 0.f);
            }
            *(float4*)&Hout[(size_t)node * TS + 4 * f] = o;
        } else {
            // tail-safe scalar stores (FOUT not multiple of 4; output stride FOUT)
            float a[4] = {acc.x, acc.y, acc.z, acc.w};
            #pragma unroll
            for (int j = 0; j < 4; ++j) {
                int c = 4 * f + j;
                if (c < FOUT) {
                    float o = a[j] * s + bias[c];
                    if (RELU) o = fmaxf(o, 0.f);
                    Hout[(size_t)node * FOUT + c] = o;
                }
            }
        }
    }
}

extern "C" void kernel_launch(void* const* d_in, const int* in_sizes, int n_in,
                              void* d_out, int out_size, void* d_ws, size_t ws_size,
                              hipStream_t stream) {
    const float* x  = (const float*)d_in[0];
    const float* W0 = (const float*)d_in[1];
    const float* b0 = (const float*)d_in[2];
    const float* W1 = (const float*)d_in[3];
    const float* b1 = (const float*)d_in[4];
    const float* W2 = (const float*)d_in[5];
    const float* b2 = (const float*)d_in[6];
    const int* src  = (const int*)d_in[7];
    const int* dst  = (const int*)d_in[8];
    float* out = (float*)d_out;

    const int N = 50000;
    const int E = in_sizes[7];
    const int NB = (N + 1023) / 1024;

    int* p = (int*)d_ws;
    int* deg_out    = p;  p += N;
    int* deg_in     = p;  p += N;
    int* row_off    = p;  p += N + 1;
    int* row_pos    = p;  p += N;
    int* blocksum   = p;  p += NB;
    int* blockoff   = p;  p += NB;
    int* src_sorted = p;  p += E;
    uintptr_t fp = ((uintptr_t)p + 15) & ~(uintptr_t)15;
    float* f = (float*)fp;
    float* norm_src = f;  f += N;
    float* norm_dst = f;  f += N;
    float* t_buf    = f;  f += (size_t)N * 64;
    float* h_buf    = f;  f += (size_t)N * 64;

    hipMemsetAsync(deg_out, 0, (size_t)2 * N * sizeof(int), stream);

    hist_kernel<<<(E + 255) / 256, 256, 0, stream>>>(src, dst, deg_out, deg_in, E);
    scan1_kernel<<<NB, 1024, 0, stream>>>(deg_in, row_off, blocksum, N);
    scan2_kernel<<<1, 64, 0, stream>>>(blocksum, blockoff, NB, &row_off[N]);
    scan3_norm_kernel<<<(N + 255) / 256, 256, 0, stream>>>(
        row_off, blockoff, row_pos, deg_out, deg_in, norm_src, norm_dst, N);
    scatter_kernel<<<(E + 255) / 256, 256, 0, stream>>>(src, dst, row_pos, src_sorted, E);

    const int gemm_grid = (N + 63) / 64;               // 782
    const int agg_grid  = (N * 64 + 255) / 256;        // 12500 (wave per node)

    // layer 0: x[N,100] -> h[N,64] (T stride 64), relu
    rowscale_gemm2<100, 64><<<gemm_grid, 256, 0, stream>>>(x, norm_src, W0, t_buf, N);
    agg2<64, 64, true><<<agg_grid, 256, 0, stream>>>(t_buf, row_off, src_sorted,
                                                     norm_dst, b0, h_buf, N);
    // layer 1: 64 -> 64, relu
    rowscale_gemm2<64, 64><<<gemm_grid, 256, 0, stream>>>(h_buf, norm_src, W1, t_buf, N);
    agg2<64, 64, true><<<agg_grid, 256, 0, stream>>>(t_buf, row_off, src_sorted,
                                                     norm_dst, b1, h_buf, N);
    // layer 2: 64 -> 47 (T stride 48), no activation, write d_out (stride 47)
    rowscale_gemm2<64, 47><<<gemm_grid, 256, 0, stream>>>(h_buf, norm_src, W2, t_buf, N);
    agg2<48, 47, false><<<agg_grid, 256, 0, stream>>>(t_buf, row_off, src_sorted,
                                                      norm_dst, b2, out, N);
}

// Round 4
// 276.017 us; speedup vs baseline: 2.5639x; 1.1326x over previous
//
#include <hip/hip_runtime.h>
#include <stdint.h>

// NSGCN: 3-layer GraphConv (norm='both'), N=50000, E=800000.
// Identity: (segsum((h*ns)[src]) * nd) @ W + b == segsum(((h*ns)@W)[src]) * nd + b
// Per layer: t = (h*ns)@W  (dense, LDS-staged, float4 everywhere)
//            h' = act(segsum_dst(t[src]) * nd + b)   (CSR gather, float4)
// CSR build v3: 8-way privatized histogram whose atomic RETURN VALUE gives each
// edge's rank -> scatter is atomic-free. deg_out packed 2 chunks/u32.

#define NCHUNK 8

// ---------------- privatized histogram + rank capture ----------------
__global__ __launch_bounds__(256) void hist_rank_kernel(
        const int* __restrict__ src, const int* __restrict__ dst,
        unsigned* __restrict__ cnt_in, unsigned* __restrict__ cnt_out_pk,
        unsigned short* __restrict__ rank, int E, int N) {
    int e = blockIdx.x * 256 + threadIdx.x;
    if (e >= E) return;
    int c = blockIdx.x & (NCHUNK - 1);
    int d = dst[e], s = src[e];
    unsigned r = atomicAdd(&cnt_in[c * N + d], 1u);       // rank within (chunk, dst)
    rank[e] = (unsigned short)r;
    atomicAdd(&cnt_out_pk[(c >> 1) * N + s], 1u << (16 * (c & 1)));
}

// ---------------- merge: chunk-prefix in place + degrees + norms ----------------
__global__ __launch_bounds__(256) void merge_kernel(
        unsigned* __restrict__ cnt_in, const unsigned* __restrict__ cnt_out_pk,
        int* __restrict__ degin, float* __restrict__ ns, float* __restrict__ nd, int N) {
    int i = blockIdx.x * 256 + threadIdx.x;
    if (i >= N) return;
    unsigned din = 0;
    #pragma unroll
    for (int c = 0; c < NCHUNK; ++c) {          // exclusive prefix over chunks, in place
        unsigned v = cnt_in[c * N + i];
        cnt_in[c * N + i] = din;
        din += v;
    }
    unsigned dout = 0;
    #pragma unroll
    for (int c = 0; c < NCHUNK / 2; ++c) {
        unsigned v = cnt_out_pk[c * N + i];
        dout += (v & 0xffffu) + (v >> 16);
    }
    degin[i] = (int)din;
    ns[i] = rsqrtf((float)(dout < 1u ? 1u : dout));
    nd[i] = rsqrtf((float)(din  < 1u ? 1u : din));
}

// ---------------- scan phase 1: per-1024-block exclusive scan ----------------
__global__ void scan1_kernel(const int* __restrict__ deg, int* __restrict__ excl,
                             int* __restrict__ blocksum, int n) {
    int i = blockIdx.x * 1024 + threadIdx.x;
    int v = (i < n) ? deg[i] : 0;
    int lane = threadIdx.x & 63;
    int wid  = threadIdx.x >> 6;
    int incl = v;
    #pragma unroll
    for (int off = 1; off < 64; off <<= 1) {
        int t = __shfl_up(incl, off, 64);
        if (lane >= off) incl += t;
    }
    __shared__ int wsum[16];
    if (lane == 63) wsum[wid] = incl;
    __syncthreads();
    if (threadIdx.x < 16) {
        int wv = wsum[threadIdx.x];
        #pragma unroll
        for (int off = 1; off < 16; off <<= 1) {
            int t = __shfl_up(wv, off, 64);
            if ((int)threadIdx.x >= off) wv += t;
        }
        wsum[threadIdx.x] = wv;
    }
    __syncthreads();
    int waveoff = (wid > 0) ? wsum[wid - 1] : 0;
    if (i < n) excl[i] = waveoff + incl - v;
    if (threadIdx.x == 1023) blocksum[blockIdx.x] = wsum[15];
}

// ---------------- scan phase 2 ----------------
__global__ void scan2_kernel(const int* __restrict__ blocksum, int* __restrict__ blockoff,
                             int nb, int* __restrict__ total_out) {
    int i = threadIdx.x;
    int v = (i < nb) ? blocksum[i] : 0;
    int incl = v;
    #pragma unroll
    for (int off = 1; off < 64; off <<= 1) {
        int t = __shfl_up(incl, off, 64);
        if (i >= off) incl += t;
    }
    if (i < nb) blockoff[i] = incl - v;
    if (i == 63) *total_out = incl;
}

// ---------------- scan phase 3: finalize row_off, absolute chunk bases ----------------
__global__ __launch_bounds__(256) void scan3_kernel(
        int* __restrict__ row_off, const int* __restrict__ blockoff,
        unsigned* __restrict__ cnt_in, int N) {
    int i = blockIdx.x * 256 + threadIdx.x;
    if (i >= N) return;
    int v = row_off[i] + blockoff[i >> 10];
    row_off[i] = v;
    #pragma unroll
    for (int c = 0; c < NCHUNK; ++c) cnt_in[c * N + i] += (unsigned)v;
}

// ---------------- atomic-free counting-sort scatter ----------------
__global__ __launch_bounds__(256) void scatter2_kernel(
        const int* __restrict__ src, const int* __restrict__ dst,
        const unsigned* __restrict__ cnt_in, const unsigned short* __restrict__ rank,
        unsigned short* __restrict__ src_sorted, int E, int N) {
    int e = blockIdx.x * 256 + threadIdx.x;
    if (e >= E) return;
    int c = blockIdx.x & (NCHUNK - 1);
    unsigned p = cnt_in[c * N + dst[e]] + rank[e];
    src_sorted[p] = (unsigned short)src[e];
}

// ---------------- fused rowscale + GEMM: T = (H * ns) @ W, stride WS ----------------
template <int FIN, int FOUT>
__global__ __launch_bounds__(256) void rowscale_gemm2(const float* __restrict__ H,
        const float* __restrict__ ns, const float* __restrict__ Wg,
        float* __restrict__ T, int n) {
    constexpr int WS = (FOUT + 3) & ~3;
    constexpr int RP = FIN + 4;
    constexpr int Q  = FIN / 4;
    __shared__ __align__(16) float Wlds[FIN * WS];
    __shared__ __align__(16) float rows[64 * RP];

    for (int i = threadIdx.x; i < FIN * WS; i += 256) {
        int k = i / WS, j = i - k * WS;
        Wlds[i] = (j < FOUT) ? Wg[k * FOUT + j] : 0.0f;
    }
    int node0 = blockIdx.x * 64;
    for (int idx = threadIdx.x; idx < 64 * Q; idx += 256) {
        int nl = idx / Q, q = idx - nl * Q;
        int node = node0 + nl;
        float4 v = make_float4(0.f, 0.f, 0.f, 0.f);
        float s = 0.f;
        if (node < n) {
            v = *(const float4*)&H[(size_t)node * FIN + 4 * q];
            s = ns[node];
        }
        float4* d4 = (float4*)&rows[nl * RP + 4 * q];
        d4->x = v.x * s; d4->y = v.y * s; d4->z = v.z * s; d4->w = v.w * s;
    }
    __syncthreads();

    int w = threadIdx.x >> 6;
    int lane = threadIdx.x & 63;
    int g = lane >> 4, f = lane & 15;
    if (4 * f < WS) {
        #pragma unroll
        for (int r = 0; r < 4; ++r) {
            int nl = w * 16 + r * 4 + g;
            const float* rp = &rows[nl * RP];
            float4 acc = make_float4(0.f, 0.f, 0.f, 0.f);
            for (int k = 0; k < FIN; ++k) {
                float hv = rp[k];
                float4 wv = *(const float4*)&Wlds[k * WS + 4 * f];
                acc.x += hv * wv.x; acc.y += hv * wv.y;
                acc.z += hv * wv.z; acc.w += hv * wv.w;
            }
            int node = node0 + nl;
            if (node < n)
                *(float4*)&T[(size_t)node * WS + 4 * f] = acc;
        }
    }
}

// ---------------- CSR aggregation: wave per dst node, float4 gather ----------------
template <int TS, int FOUT, bool RELU>
__global__ __launch_bounds__(256) void agg2(const float* __restrict__ T,
        const int* __restrict__ row_off, const unsigned short* __restrict__ srcs,
        const float* __restrict__ nd, const float* __restrict__ bias,
        float* __restrict__ Hout, int n) {
    int node = (blockIdx.x * 256 + threadIdx.x) >> 6;
    int lane = threadIdx.x & 63;
    int g = lane >> 4, f = lane & 15;
    if (node >= n) return;
    int beg = row_off[node], end = row_off[node + 1];
    float4 acc = make_float4(0.f, 0.f, 0.f, 0.f);
    if (4 * f < TS) {
        for (int e = beg + g; e < end; e += 4) {
            int s = srcs[e];
            float4 v = *(const float4*)&T[(size_t)s * TS + 4 * f];
            acc.x += v.x; acc.y += v.y; acc.z += v.z; acc.w += v.w;
        }
    }
    #pragma unroll
    for (int m = 16; m <= 32; m <<= 1) {
        acc.x += __shfl_xor(acc.x, m, 64);
        acc.y += __shfl_xor(acc.y, m, 64);
        acc.z += __shfl_xor(acc.z, m, 64);
        acc.w += __shfl_xor(acc.w, m, 64);
    }
    if (g == 0 && 4 * f < TS) {
        float s = nd[node];
        if (TS == FOUT) {
            float4 o;
            o.x = acc.x * s + bias[4 * f + 0];
            o.y = acc.y * s + bias[4 * f + 1];
            o.z = acc.z * s + bias[4 * f + 2];
            o.w = acc.w * s + bias[4 * f + 3];
            if (RELU) {
                o.x = fmaxf(o.x, 0.f); o.y = fmaxf(o.y, 0.f);
                o.z = fmaxf(o.z, 0.f); o.w = fmaxf(o.w, 0.f);
            }
            *(float4*)&Hout[(size_t)node * TS + 4 * f] = o;
        } else {
            float a[4] = {acc.x, acc.y, acc.z, acc.w};
            #pragma unroll
            for (int j = 0; j < 4; ++j) {
                int c = 4 * f + j;
                if (c < FOUT) {
                    float o = a[j] * s + bias[c];
                    if (RELU) o = fmaxf(o, 0.f);
                    Hout[(size_t)node * FOUT + c] = o;
                }
            }
        }
    }
}

extern "C" void kernel_launch(void* const* d_in, const int* in_sizes, int n_in,
                              void* d_out, int out_size, void* d_ws, size_t ws_size,
                              hipStream_t stream) {
    const float* x  = (const float*)d_in[0];
    const float* W0 = (const float*)d_in[1];
    const float* b0 = (const float*)d_in[2];
    const float* W1 = (const float*)d_in[3];
    const float* b1 = (const float*)d_in[4];
    const float* W2 = (const float*)d_in[5];
    const float* b2 = (const float*)d_in[6];
    const int* src  = (const int*)d_in[7];
    const int* dst  = (const int*)d_in[8];
    float* out = (float*)d_out;

    const int N = 50000;
    const int E = in_sizes[7];
    const int NB = (N + 1023) / 1024;   // 49 <= 64

    // ---- workspace layout ----
    unsigned* u = (unsigned*)d_ws;
    unsigned* cnt_in     = u;  u += (size_t)NCHUNK * N;        // 8 planes
    unsigned* cnt_out_pk = u;  u += (size_t)(NCHUNK / 2) * N;  // 4 packed planes
    int* p = (int*)u;
    int* degin    = p;  p += N;
    int* row_off  = p;  p += N + 1;
    int* blocksum = p;  p += 64;
    int* blockoff = p;  p += 64;
    unsigned short* rank       = (unsigned short*)p;
    unsigned short* src_sorted = rank + E;
    uintptr_t fp = ((uintptr_t)(src_sorted + E) + 15) & ~(uintptr_t)15;
    float* f = (float*)fp;
    float* norm_src = f;  f += N;
    float* norm_dst = f;  f += N;
    float* t_buf    = f;  f += (size_t)N * 64;
    float* h_buf    = f;  f += (size_t)N * 64;

    // zero the 12 contiguous counter planes
    hipMemsetAsync(cnt_in, 0, (size_t)(NCHUNK + NCHUNK / 2) * N * sizeof(unsigned), stream);

    const int egrid = (E + 255) / 256;   // 3125 (chunk = blockIdx & 7, same in both)
    hist_rank_kernel<<<egrid, 256, 0, stream>>>(src, dst, cnt_in, cnt_out_pk, rank, E, N);
    merge_kernel<<<(N + 255) / 256, 256, 0, stream>>>(cnt_in, cnt_out_pk, degin,
                                                      norm_src, norm_dst, N);
    scan1_kernel<<<NB, 1024, 0, stream>>>(degin, row_off, blocksum, N);
    scan2_kernel<<<1, 64, 0, stream>>>(blocksum, blockoff, NB, &row_off[N]);
    scan3_kernel<<<(N + 255) / 256, 256, 0, stream>>>(row_off, blockoff, cnt_in, N);
    scatter2_kernel<<<egrid, 256, 0, stream>>>(src, dst, cnt_in, rank, src_sorted, E, N);

    const int gemm_grid = (N + 63) / 64;
    const int agg_grid  = (N * 64 + 255) / 256;

    rowscale_gemm2<100, 64><<<gemm_grid, 256, 0, stream>>>(x, norm_src, W0, t_buf, N);
    agg2<64, 64, true><<<agg_grid, 256, 0, stream>>>(t_buf, row_off, src_sorted,
                                                     norm_dst, b0, h_buf, N);
    rowscale_gemm2<64, 64><<<gemm_grid, 256, 0, stream>>>(h_buf, norm_src, W1, t_buf, N);
    agg2<64, 64, true><<<agg_grid, 256, 0, stream>>>(t_buf, row_off, src_sorted,
                                                     norm_dst, b1, h_buf, N);
    rowscale_gemm2<64, 47><<<gemm_grid, 256, 0, stream>>>(h_buf, norm_src, W2, t_buf, N);
    agg2<48, 47, false><<<agg_grid, 256, 0, stream>>>(t_buf, row_off, src_sorted,
                                                      norm_dst, b2, out, N);
}

// Round 5
// 244.855 us; speedup vs baseline: 2.8902x; 1.1273x over previous
//
#include <hip/hip_runtime.h>
#include <stdint.h>

// NSGCN: 3-layer GraphConv (norm='both'), N=50000, E=800000.
// Identity: (segsum((h*ns)[src]) * nd) @ W + b == segsum(((h*ns)@W)[src]) * nd + b
// CSR build v4: ZERO global atomics. 64 blocks x 1024 thr; each block holds its
// ~13K edges in registers and builds packed-u16 LDS histograms over the node
// range in two 25K-node phases (LDS atomic return = local rank). Per-node
// cross-block prefix (merge) + block scan -> absolute bases -> pure-store scatter.
// Count planes alias t_buf (dead until gemm0); rank aliases h_buf.

#define HB   64      // hist blocks
#define HT   1024    // hist threads/block
#define EPT  13      // edges per thread
#define EPB  (HT * EPT)          // 13312 edges per block
#define HALF 25000               // nodes per LDS phase
#define HW   (HALF / 2)          // 12500 packed u32 words per phase
#define NW   25000               // total packed words per plane (N/2)

// ---------------- K1: LDS histogram + rank capture ----------------
__global__ __launch_bounds__(1024) void hist_lds_kernel(
        const int* __restrict__ src, const int* __restrict__ dst,
        unsigned* __restrict__ cnt_dst, unsigned* __restrict__ cnt_src,
        unsigned short* __restrict__ rank, int E) {
    __shared__ unsigned h[HW];   // 50 KB
    int b = blockIdx.x;
    int base = b * EPB;
    int s[EPT], d[EPT];
    bool val[EPT];
    unsigned short rk[EPT];
    #pragma unroll
    for (int j = 0; j < EPT; ++j) {
        int e = base + j * HT + (int)threadIdx.x;
        val[j] = (e < E);
        s[j] = val[j] ? src[e] : 0;
        d[j] = val[j] ? dst[e] : 0;
        rk[j] = 0;
    }
    // dst phases (rank captured from LDS atomic return)
    for (int ph = 0; ph < 2; ++ph) {
        for (int w = threadIdx.x; w < HW; w += HT) h[w] = 0;
        __syncthreads();
        int lo = ph * HALF;
        #pragma unroll
        for (int j = 0; j < EPT; ++j) {
            int dd = d[j] - lo;
            if (val[j] && (unsigned)dd < (unsigned)HALF) {
                unsigned sh = 16u * (dd & 1);
                unsigned old = atomicAdd(&h[dd >> 1], 1u << sh);
                rk[j] = (unsigned short)((old >> sh) & 0xffffu);
            }
        }
        __syncthreads();
        for (int w = threadIdx.x; w < HW; w += HT)
            cnt_dst[(size_t)b * NW + ph * HW + w] = h[w];
        __syncthreads();
    }
    #pragma unroll
    for (int j = 0; j < EPT; ++j) {
        int e = base + j * HT + (int)threadIdx.x;
        if (val[j]) rank[e] = rk[j];
    }
    // src phases (counts only)
    for (int ph = 0; ph < 2; ++ph) {
        for (int w = threadIdx.x; w < HW; w += HT) h[w] = 0;
        __syncthreads();
        int lo = ph * HALF;
        #pragma unroll
        for (int j = 0; j < EPT; ++j) {
            int ss = s[j] - lo;
            if (val[j] && (unsigned)ss < (unsigned)HALF)
                atomicAdd(&h[ss >> 1], 1u << (16u * (ss & 1)));
        }
        __syncthreads();
        for (int w = threadIdx.x; w < HW; w += HT)
            cnt_src[(size_t)b * NW + ph * HW + w] = h[w];
        __syncthreads();
    }
}

// ---------------- K2: cross-block prefix (in place) + degrees + norms ----------------
// NOTE: per-node prefix fits u16 because max in-degree of this (uniform random)
// graph is ~50 << 65536.
__global__ __launch_bounds__(256) void merge2_kernel(
        unsigned* __restrict__ cnt_dst, const unsigned* __restrict__ cnt_src,
        int* __restrict__ degin, float* __restrict__ ns, float* __restrict__ nd,
        int nw) {
    int w = blockIdx.x * 256 + threadIdx.x;
    if (w >= nw) return;
    unsigned p0 = 0, p1 = 0;
    #pragma unroll 8
    for (int b = 0; b < HB; ++b) {
        unsigned v = cnt_dst[(size_t)b * NW + w];
        cnt_dst[(size_t)b * NW + w] = p0 | (p1 << 16);
        p0 += v & 0xffffu;
        p1 += v >> 16;
    }
    unsigned q0 = 0, q1 = 0;
    #pragma unroll 8
    for (int b = 0; b < HB; ++b) {
        unsigned v = cnt_src[(size_t)b * NW + w];
        q0 += v & 0xffffu;
        q1 += v >> 16;
    }
    degin[2 * w]     = (int)p0;
    degin[2 * w + 1] = (int)p1;
    nd[2 * w]     = rsqrtf((float)(p0 < 1u ? 1u : p0));
    nd[2 * w + 1] = rsqrtf((float)(p1 < 1u ? 1u : p1));
    ns[2 * w]     = rsqrtf((float)(q0 < 1u ? 1u : q0));
    ns[2 * w + 1] = rsqrtf((float)(q1 < 1u ? 1u : q1));
}

// ---------------- scan phase 1: per-1024-block exclusive scan ----------------
__global__ void scan1_kernel(const int* __restrict__ deg, int* __restrict__ excl,
                             int* __restrict__ blocksum, int n) {
    int i = blockIdx.x * 1024 + threadIdx.x;
    int v = (i < n) ? deg[i] : 0;
    int lane = threadIdx.x & 63;
    int wid  = threadIdx.x >> 6;
    int incl = v;
    #pragma unroll
    for (int off = 1; off < 64; off <<= 1) {
        int t = __shfl_up(incl, off, 64);
        if (lane >= off) incl += t;
    }
    __shared__ int wsum[16];
    if (lane == 63) wsum[wid] = incl;
    __syncthreads();
    if (threadIdx.x < 16) {
        int wv = wsum[threadIdx.x];
        #pragma unroll
        for (int off = 1; off < 16; off <<= 1) {
            int t = __shfl_up(wv, off, 64);
            if ((int)threadIdx.x >= off) wv += t;
        }
        wsum[threadIdx.x] = wv;
    }
    __syncthreads();
    int waveoff = (wid > 0) ? wsum[wid - 1] : 0;
    if (i < n) excl[i] = waveoff + incl - v;
    if (threadIdx.x == 1023) blocksum[blockIdx.x] = wsum[15];
}

// ---------------- scan phase 2 ----------------
__global__ void scan2_kernel(const int* __restrict__ blocksum, int* __restrict__ blockoff,
                             int nb, int* __restrict__ total_out) {
    int i = threadIdx.x;
    int v = (i < nb) ? blocksum[i] : 0;
    int incl = v;
    #pragma unroll
    for (int off = 1; off < 64; off <<= 1) {
        int t = __shfl_up(incl, off, 64);
        if (i >= off) incl += t;
    }
    if (i < nb) blockoff[i] = incl - v;
    if (i == 63) *total_out = incl;
}

// ---------------- scan phase 3: finalize row_off ----------------
__global__ __launch_bounds__(256) void scan3b_kernel(int* __restrict__ row_off,
        const int* __restrict__ blockoff, int n) {
    int i = blockIdx.x * 256 + threadIdx.x;
    if (i < n) row_off[i] += blockoff[i >> 10];
}

// ---------------- K5: atomic-free scatter ----------------
__global__ __launch_bounds__(1024) void scatter3_kernel(
        const int* __restrict__ src, const int* __restrict__ dst,
        const unsigned* __restrict__ cnt_dst, const int* __restrict__ row_off,
        const unsigned short* __restrict__ rank,
        unsigned short* __restrict__ src_sorted, int E) {
    int b = blockIdx.x;
    int base = b * EPB;
    #pragma unroll
    for (int j = 0; j < EPT; ++j) {
        int e = base + j * HT + (int)threadIdx.x;
        if (e >= E) continue;
        int d = dst[e];
        unsigned pk = cnt_dst[(size_t)b * NW + (d >> 1)];
        unsigned pfx = (pk >> (16u * (d & 1))) & 0xffffu;
        unsigned p = (unsigned)row_off[d] + pfx + (unsigned)rank[e];
        src_sorted[p] = (unsigned short)src[e];
    }
}

// ---------------- fused rowscale + GEMM: T = (H * ns) @ W, stride WS ----------------
// 64 nodes/block; wave = 4 node-groups x 16 lanes; lane owns feature quad.
// Inner loop: one W float4 per k shared by 4 rows (4x fewer ds_read_b128).
template <int FIN, int FOUT>
__global__ __launch_bounds__(256) void rowscale_gemm2(const float* __restrict__ H,
        const float* __restrict__ ns, const float* __restrict__ Wg,
        float* __restrict__ T, int n) {
    constexpr int WS = (FOUT + 3) & ~3;
    constexpr int RP = FIN + 4;
    constexpr int Q  = FIN / 4;
    __shared__ __align__(16) float Wlds[FIN * WS];
    __shared__ __align__(16) float rows[64 * RP];

    for (int i = threadIdx.x; i < FIN * WS; i += 256) {
        int k = i / WS, j = i - k * WS;
        Wlds[i] = (j < FOUT) ? Wg[k * FOUT + j] : 0.0f;
    }
    int node0 = blockIdx.x * 64;
    for (int idx = threadIdx.x; idx < 64 * Q; idx += 256) {
        int nl = idx / Q, q = idx - nl * Q;
        int node = node0 + nl;
        float4 v = make_float4(0.f, 0.f, 0.f, 0.f);
        float s = 0.f;
        if (node < n) {
            v = *(const float4*)&H[(size_t)node * FIN + 4 * q];
            s = ns[node];
        }
        float4* d4 = (float4*)&rows[nl * RP + 4 * q];
        d4->x = v.x * s; d4->y = v.y * s; d4->z = v.z * s; d4->w = v.w * s;
    }
    __syncthreads();

    int w = threadIdx.x >> 6;
    int lane = threadIdx.x & 63;
    int g = lane >> 4, f = lane & 15;
    if (4 * f < WS) {
        float4 acc0 = make_float4(0.f,0.f,0.f,0.f), acc1 = acc0, acc2 = acc0, acc3 = acc0;
        const float* r0 = &rows[(w * 16 + 0 * 4 + g) * RP];
        const float* r1 = &rows[(w * 16 + 1 * 4 + g) * RP];
        const float* r2 = &rows[(w * 16 + 2 * 4 + g) * RP];
        const float* r3 = &rows[(w * 16 + 3 * 4 + g) * RP];
        for (int k = 0; k < FIN; ++k) {
            float4 wv = *(const float4*)&Wlds[k * WS + 4 * f];
            float h0 = r0[k], h1 = r1[k], h2 = r2[k], h3 = r3[k];
            acc0.x += h0 * wv.x; acc0.y += h0 * wv.y; acc0.z += h0 * wv.z; acc0.w += h0 * wv.w;
            acc1.x += h1 * wv.x; acc1.y += h1 * wv.y; acc1.z += h1 * wv.z; acc1.w += h1 * wv.w;
            acc2.x += h2 * wv.x; acc2.y += h2 * wv.y; acc2.z += h2 * wv.z; acc2.w += h2 * wv.w;
            acc3.x += h3 * wv.x; acc3.y += h3 * wv.y; acc3.z += h3 * wv.z; acc3.w += h3 * wv.w;
        }
        float4 accs[4] = {acc0, acc1, acc2, acc3};
        #pragma unroll
        for (int r = 0; r < 4; ++r) {
            int node = node0 + w * 16 + r * 4 + g;
            if (node < n)
                *(float4*)&T[(size_t)node * WS + 4 * f] = accs[r];
        }
    }
}

// ---------------- CSR aggregation: wave per dst node, float4 gather ----------------
template <int TS, int FOUT, bool RELU>
__global__ __launch_bounds__(256) void agg2(const float* __restrict__ T,
        const int* __restrict__ row_off, const unsigned short* __restrict__ srcs,
        const float* __restrict__ nd, const float* __restrict__ bias,
        float* __restrict__ Hout, int n) {
    int node = (blockIdx.x * 256 + threadIdx.x) >> 6;
    int lane = threadIdx.x & 63;
    int g = lane >> 4, f = lane & 15;
    if (node >= n) return;
    int beg = row_off[node], end = row_off[node + 1];
    float4 acc = make_float4(0.f, 0.f, 0.f, 0.f);
    if (4 * f < TS) {
        for (int e = beg + g; e < end; e += 4) {
            int s = srcs[e];
            float4 v = *(const float4*)&T[(size_t)s * TS + 4 * f];
            acc.x += v.x; acc.y += v.y; acc.z += v.z; acc.w += v.w;
        }
    }
    #pragma unroll
    for (int m = 16; m <= 32; m <<= 1) {
        acc.x += __shfl_xor(acc.x, m, 64);
        acc.y += __shfl_xor(acc.y, m, 64);
        acc.z += __shfl_xor(acc.z, m, 64);
        acc.w += __shfl_xor(acc.w, m, 64);
    }
    if (g == 0 && 4 * f < TS) {
        float s = nd[node];
        if (TS == FOUT) {
            float4 o;
            o.x = acc.x * s + bias[4 * f + 0];
            o.y = acc.y * s + bias[4 * f + 1];
            o.z = acc.z * s + bias[4 * f + 2];
            o.w = acc.w * s + bias[4 * f + 3];
            if (RELU) {
                o.x = fmaxf(o.x, 0.f); o.y = fmaxf(o.y, 0.f);
                o.z = fmaxf(o.z, 0.f); o.w = fmaxf(o.w, 0.f);
            }
            *(float4*)&Hout[(size_t)node * TS + 4 * f] = o;
        } else {
            float a[4] = {acc.x, acc.y, acc.z, acc.w};
            #pragma unroll
            for (int j = 0; j < 4; ++j) {
                int c = 4 * f + j;
                if (c < FOUT) {
                    float o = a[j] * s + bias[c];
                    if (RELU) o = fmaxf(o, 0.f);
                    Hout[(size_t)node * FOUT + c] = o;
                }
            }
        }
    }
}

extern "C" void kernel_launch(void* const* d_in, const int* in_sizes, int n_in,
                              void* d_out, int out_size, void* d_ws, size_t ws_size,
                              hipStream_t stream) {
    const float* x  = (const float*)d_in[0];
    const float* W0 = (const float*)d_in[1];
    const float* b0 = (const float*)d_in[2];
    const float* W1 = (const float*)d_in[3];
    const float* b1 = (const float*)d_in[4];
    const float* W2 = (const float*)d_in[5];
    const float* b2 = (const float*)d_in[6];
    const int* src  = (const int*)d_in[7];
    const int* dst  = (const int*)d_in[8];
    float* out = (float*)d_out;

    const int N = 50000;
    const int E = in_sizes[7];
    const int NB = (N + 1023) / 1024;   // 49 <= 64

    // ---- workspace layout ----
    int* p = (int*)d_ws;
    int* degin    = p;  p += N;
    int* row_off  = p;  p += N + 1;
    int* blocksum = p;  p += 64;
    int* blockoff = p;  p += 64;
    unsigned short* src_sorted = (unsigned short*)p;           // E u16
    uintptr_t fp = ((uintptr_t)(src_sorted + E) + 15) & ~(uintptr_t)15;
    float* f = (float*)fp;
    float* norm_src = f;  f += N;
    float* norm_dst = f;  f += N;
    float* t_buf    = f;  f += (size_t)N * 64;
    float* h_buf    = f;  f += (size_t)N * 64;
    // CSR-build aliases (dead before gemm0/agg0 write them):
    unsigned* cnt_dst = (unsigned*)t_buf;                      // HB*NW u32 = 6.4 MB
    unsigned* cnt_src = cnt_dst + (size_t)HB * NW;             // 6.4 MB (fills t_buf)
    unsigned short* rank = (unsigned short*)h_buf;             // 1.6 MB

    hist_lds_kernel<<<HB, HT, 0, stream>>>(src, dst, cnt_dst, cnt_src, rank, E);
    merge2_kernel<<<(NW + 255) / 256, 256, 0, stream>>>(cnt_dst, cnt_src, degin,
                                                        norm_src, norm_dst, NW);
    scan1_kernel<<<NB, 1024, 0, stream>>>(degin, row_off, blocksum, N);
    scan2_kernel<<<1, 64, 0, stream>>>(blocksum, blockoff, NB, &row_off[N]);
    scan3b_kernel<<<(N + 255) / 256, 256, 0, stream>>>(row_off, blockoff, N);
    scatter3_kernel<<<HB, HT, 0, stream>>>(src, dst, cnt_dst, row_off, rank,
                                           src_sorted, E);

    const int gemm_grid = (N + 63) / 64;
    const int agg_grid  = (N * 64 + 255) / 256;

    rowscale_gemm2<100, 64><<<gemm_grid, 256, 0, stream>>>(x, norm_src, W0, t_buf, N);
    agg2<64, 64, true><<<agg_grid, 256, 0, stream>>>(t_buf, row_off, src_sorted,
                                                     norm_dst, b0, h_buf, N);
    rowscale_gemm2<64, 64><<<gemm_grid, 256, 0, stream>>>(h_buf, norm_src, W1, t_buf, N);
    agg2<64, 64, true><<<agg_grid, 256, 0, stream>>>(t_buf, row_off, src_sorted,
                                                     norm_dst, b1, h_buf, N);
    rowscale_gemm2<64, 47><<<gemm_grid, 256, 0, stream>>>(h_buf, norm_src, W2, t_buf, N);
    agg2<48, 47, false><<<agg_grid, 256, 0, stream>>>(t_buf, row_off, src_sorted,
                                                      norm_dst, b2, out, N);
}